// Round 9
// baseline (482.163 us; speedup 1.0000x reference)
//
#include <hip/hip_runtime.h>

// ChainMessagePassing: out[n] = sum over edges with dst==n of x[src], over two edge lists.
// x: [N=100000, 64] fp32; indices: [2, E=3200000] (src row 0, dst row 1), int64 or int32.
//
// R12: fill the empty ablation cell. 3-point gather ablation (R9/R10/R11, all ~205us):
//   tile-major MLP4 = latency-bound (FETCH 136MB, VALU 17%);
//   concat+ADDP MLP8 = VALU-bound (73%, 21 ops/edge);
//   node-major MLP8 = fetch-bound (670MB, tile sync lost).
// Fix: tile-major key, and walk the group's 4 ADJACENT bins (its 4 nodes at tile t)
// as 4 concurrent runs, 2 edges each per iteration = 8 loads in flight, each run
// feeding its OWN named accumulator with plain adds (static mapping, no predication).
// ~7 VALU ops/edge, MLP 8, strict tile sweep kept (FETCH ~136MB).
// Scatter: CHUNK 4096->8192 @512 threads: 2.6->5.2 edges per bucket sub-run halves
// the ~6x partial-line write amplification (same mechanism as R5/R7/R8, 10B grain).

static constexpr int D = 64;
static constexpr int Q = 16;          // float4 quads per row
static constexpr int NPB = 64;        // nodes per bucket
static constexpr int NPB_SHIFT = 6;
static constexpr int CHUNK = 8192;    // edges per scatter block (16/thread @512)
static constexpr int CH = 4096;       // edges per gather sort chunk (16 KB LDS)
static constexpr int MAXT = 32;       // max src tiles (nbins <= 2048)

// ---- index dtype sniffer: int64 nonneg <2^31 has all-zero odd dwords ----
__global__ void detect_idx_dtype(const int* __restrict__ w, int* __restrict__ flag) {
    int tid = threadIdx.x;  // one wave
    int v = w[2 * tid + 1];
    unsigned long long m = __ballot(v != 0);
    if (tid == 0) *flag = (m == 0ULL) ? 1 : 0;
}

__device__ __forceinline__ int load_idx_nt(const void* idx, long long i, int is64) {
    return is64 ? (int)__builtin_nontemporal_load(((const long long*)idx) + i)
                : __builtin_nontemporal_load(((const int*)idx) + i);
}

// ---- phase 1: bucket histogram, LDS-aggregated ----
__global__ __launch_bounds__(256) void bucket_hist_kernel(
        const void* __restrict__ up, const void* __restrict__ down,
        int* __restrict__ bcounts, const int* __restrict__ flag, int E, int NB) {
    extern __shared__ int lcnt[];
    const int is64 = *flag;
    for (int i = threadIdx.x; i < NB; i += blockDim.x) lcnt[i] = 0;
    __syncthreads();
    const long long total = 2LL * E;
    const long long stride = (long long)gridDim.x * blockDim.x;
    for (long long e = (long long)blockIdx.x * blockDim.x + threadIdx.x;
         e < total; e += stride) {
        const void* idx = up; long long ee = e;
        if (ee >= E) { idx = down; ee -= E; }
        int dst = load_idx_nt(idx, E + ee, is64);
        atomicAdd(&lcnt[dst >> NPB_SHIFT], 1);
    }
    __syncthreads();
    for (int i = threadIdx.x; i < NB; i += blockDim.x)
        if (lcnt[i]) atomicAdd(&bcounts[i], lcnt[i]);
}

// ---- phase 2: exclusive scan over NB buckets, one block ----
__global__ __launch_bounds__(1024) void scan_kernel(
        const int* __restrict__ counts, int* __restrict__ offsets,
        int* __restrict__ cursors, int NB) {
    __shared__ int sums[1024];
    const int tid = threadIdx.x;
    const int chunk = (NB + 1023) / 1024;
    const int start = tid * chunk;
    const int end = min(start + chunk, NB);
    int s = 0;
    for (int i = start; i < end; i++) s += counts[i];
    sums[tid] = s;
    __syncthreads();
    for (int off = 1; off < 1024; off <<= 1) {
        int t = (tid >= off) ? sums[tid - off] : 0;
        __syncthreads();
        sums[tid] += t;
        __syncthreads();
    }
    int run = (tid == 0) ? 0 : sums[tid - 1];
    for (int i = start; i < end; i++) {
        offsets[i] = run;
        cursors[i] = run;
        run += counts[i];
    }
    if (tid == 1023) offsets[NB] = run;
}

// ---- phase 3: scatter packed (src<<6 | dst&63) into bucket bins ----
// SINGLE global read pass @512 threads, CHUNK 8192: (packed,bucket) register-
// staged (16/thread), LDS histogram -> one global atomicAdd per (block,bucket)
// reserves a contiguous sub-run (~5.2 edges = 21B/line, halved write amp).
__global__ __launch_bounds__(512) void bucket_scatter_kernel(
        const void* __restrict__ up, const void* __restrict__ down,
        int* __restrict__ gcursor, unsigned* __restrict__ packed,
        const int* __restrict__ flag, int E, int NB) {
    extern __shared__ int lds[];
    int* cnt = lds;        // [NB]
    int* base = lds + NB;  // [NB]
    const int is64 = *flag;
    const long long total = 2LL * E;
    const long long cs = (long long)blockIdx.x * CHUNK;
    if (cs >= total) return;
    const int m = (int)(min(total, cs + (long long)CHUNK) - cs);
    const int tid = threadIdx.x;

    for (int i = tid; i < NB; i += 512) cnt[i] = 0;
    __syncthreads();

    unsigned pr[16];
    int bkt[16];
    #pragma unroll
    for (int k = 0; k < 16; k++) {
        const int i = tid + (k << 9);
        bkt[k] = -1;
        if (i < m) {
            long long e = cs + i;
            const void* idx = up; long long ee = e;
            if (ee >= E) { idx = down; ee -= E; }
            const int src = load_idx_nt(idx, ee, is64);
            const int dst = load_idx_nt(idx, E + ee, is64);
            pr[k] = ((unsigned)src << NPB_SHIFT) | (unsigned)(dst & (NPB - 1));
            bkt[k] = dst >> NPB_SHIFT;
            atomicAdd(&cnt[bkt[k]], 1);
        }
    }
    __syncthreads();
    for (int i = tid; i < NB; i += 512) {
        int c = cnt[i];
        base[i] = c ? atomicAdd(&gcursor[i], c) : 0;
        cnt[i] = 0;  // reuse as local cursor
    }
    __syncthreads();
    #pragma unroll
    for (int k = 0; k < 16; k++) {
        if (bkt[k] >= 0) {
            int pos = base[bkt[k]] + atomicAdd(&cnt[bkt[k]], 1);
            packed[pos] = pr[k];
        }
    }
}

// ---- phase 4: per-bucket counting sort by (src-tile, dstlo) TILE-MAJOR +
// 4-run concurrent gather. Group g (16 lanes) owns nodes 4g..4g+3 = bins
// kb..kb+3 at each tile: walk all 4 runs 2-deep concurrently (8 loads in
// flight), each run into its own named acc with plain adds. Strict per-tile
// sweep keeps chip-wide x working set ~1 tile (2MB, L2-resident). ----
__global__ __launch_bounds__(256) void bucket_gather_kernel(
        const float* __restrict__ x, const int* __restrict__ offsets,
        const unsigned* __restrict__ packed, float* __restrict__ out,
        int N, int shift, int NT) {
    extern __shared__ int lds[];
    unsigned* sorted = (unsigned*)lds;        // [CH]
    int* cnt = lds + CH;                      // [nbins] -> becomes cursor
    int* binoff = cnt + NT * NPB;             // [nbins+1]
    const int nbins = NT * NPB;

    const int b = blockIdx.x;
    const int tid = threadIdx.x;
    const int g = tid >> 4;   // group 0..15 (owns nodes 4g..4g+3)
    const int q = tid & 15;   // quad within row
    const int beg = offsets[b], end = offsets[b + 1];
    const float* xq = x + q * 4;

    float4 acc0 = make_float4(0.f, 0.f, 0.f, 0.f);
    float4 acc1 = acc0, acc2 = acc0, acc3 = acc0;

#define LOAD1(E) (*(const float4*)(xq + ((long long)(sorted[E] >> NPB_SHIFT)) * D))
#define DRAIN(A, E, RE) do {                                                   \
        for (; (E) + 4 <= (RE); (E) += 4) {                                    \
            const float4 w0 = LOAD1((E) + 0), w1 = LOAD1((E) + 1);             \
            const float4 w2 = LOAD1((E) + 2), w3 = LOAD1((E) + 3);             \
            A.x += (w0.x + w1.x) + (w2.x + w3.x);                              \
            A.y += (w0.y + w1.y) + (w2.y + w3.y);                              \
            A.z += (w0.z + w1.z) + (w2.z + w3.z);                              \
            A.w += (w0.w + w1.w) + (w2.w + w3.w);                              \
        }                                                                      \
        for (; (E) < (RE); (E)++) {                                            \
            const float4 w = LOAD1(E);                                         \
            A.x += w.x; A.y += w.y; A.z += w.z; A.w += w.w;                    \
        }                                                                      \
    } while (0)

    for (int cs = beg; cs < end; cs += CH) {
        const int m = min(CH, end - cs);
        for (int i = tid; i < nbins; i += 256) cnt[i] = 0;
        __syncthreads();
        // hist + register stage (CH == 16*256); key = tile*NPB + dstlo
        unsigned pr[16];
        #pragma unroll
        for (int k = 0; k < 16; k++) {
            const int i = tid + (k << 8);
            if (i < m) {
                unsigned p = __builtin_nontemporal_load(packed + cs + i);
                pr[k] = p;
                int key = (int)((p >> (NPB_SHIFT + shift)) << NPB_SHIFT) | (int)(p & (NPB - 1));
                atomicAdd(&cnt[key], 1);
            }
        }
        __syncthreads();
        if (tid < 64) {  // wave 0: scan over nbins; cnt becomes exclusive cursor
            const int K = (nbins + 63) >> 6;
            const int base = tid * K;
            int S = 0;
            for (int k = 0; k < K; k++) {
                int i = base + k;
                if (i < nbins) S += cnt[i];
            }
            int inc = S;
            #pragma unroll
            for (int off = 1; off < 64; off <<= 1) {
                int t = __shfl_up(inc, off, 64);
                if (tid >= off) inc += t;
            }
            int run = inc - S;  // exclusive lane offset
            for (int k = 0; k < K; k++) {
                int i = base + k;
                if (i < nbins) {
                    int c = cnt[i];
                    cnt[i] = run;
                    binoff[i + 1] = run + c;
                    run += c;
                }
            }
            if (tid == 0) binoff[0] = 0;
        }
        __syncthreads();
        #pragma unroll
        for (int k = 0; k < 16; k++) {
            const int i = tid + (k << 8);
            if (i < m) {
                unsigned p = pr[k];
                int key = (int)((p >> (NPB_SHIFT + shift)) << NPB_SHIFT) | (int)(p & (NPB - 1));
                int pos = atomicAdd(&cnt[key], 1);
                sorted[pos] = p;
            }
        }
        __syncthreads();

        // per tile: 4 adjacent bins (the group's 4 nodes) walked concurrently,
        // 2 edges each per iteration = 8 loads in flight, static acc mapping.
        for (int t = 0; t < NT; t++) {
            const int kb = t * NPB + 4 * g;
            const int c0 = binoff[kb], c1 = binoff[kb + 1], c2 = binoff[kb + 2];
            const int c3 = binoff[kb + 3], c4 = binoff[kb + 4];
            int e0 = c0, e1 = c1, e2 = c2, e3 = c3;
            while (e0 + 2 <= c1 && e1 + 2 <= c2 && e2 + 2 <= c3 && e3 + 2 <= c4) {
                const float4 u0 = LOAD1(e0), u1 = LOAD1(e0 + 1);
                const float4 u2 = LOAD1(e1), u3 = LOAD1(e1 + 1);
                const float4 u4 = LOAD1(e2), u5 = LOAD1(e2 + 1);
                const float4 u6 = LOAD1(e3), u7 = LOAD1(e3 + 1);
                acc0.x += u0.x + u1.x; acc0.y += u0.y + u1.y;
                acc0.z += u0.z + u1.z; acc0.w += u0.w + u1.w;
                acc1.x += u2.x + u3.x; acc1.y += u2.y + u3.y;
                acc1.z += u2.z + u3.z; acc1.w += u2.w + u3.w;
                acc2.x += u4.x + u5.x; acc2.y += u4.y + u5.y;
                acc2.z += u4.z + u5.z; acc2.w += u4.w + u5.w;
                acc3.x += u6.x + u7.x; acc3.y += u6.y + u7.y;
                acc3.z += u6.z + u7.z; acc3.w += u6.w + u7.w;
                e0 += 2; e1 += 2; e2 += 2; e3 += 2;
            }
            DRAIN(acc0, e0, c1);
            DRAIN(acc1, e1, c2);
            DRAIN(acc2, e2, c3);
            DRAIN(acc3, e3, c4);
        }
        __syncthreads();  // gather reads done before next chunk reuses LDS
    }
#undef DRAIN
#undef LOAD1

    const int node0 = b * NPB + 4 * g;
    if (node0 < N)
        *(float4*)(out + (long long)node0 * D + q * 4) = acc0;
    if (node0 + 1 < N)
        *(float4*)(out + (long long)(node0 + 1) * D + q * 4) = acc1;
    if (node0 + 2 < N)
        *(float4*)(out + (long long)(node0 + 2) * D + q * 4) = acc2;
    if (node0 + 3 < N)
        *(float4*)(out + (long long)(node0 + 3) * D + q * 4) = acc3;
}

// ---- fallback: direct fp32 atomics (R1), needs no workspace ----
__global__ __launch_bounds__(256) void scatter_add_kernel(
        const float* __restrict__ x, const void* __restrict__ up_idx,
        const void* __restrict__ down_idx, float* __restrict__ out,
        const int* __restrict__ dtype_flag, int num_edges) {
    const int is64 = *dtype_flag;
    const long long total = 2LL * num_edges * Q;
    const long long stride = (long long)gridDim.x * blockDim.x;
    for (long long t = (long long)blockIdx.x * blockDim.x + threadIdx.x;
         t < total; t += stride) {
        const int quad = (int)(t & (Q - 1));
        long long eg = t >> 4;
        const void* idx = up_idx;
        if (eg >= num_edges) { idx = down_idx; eg -= num_edges; }
        int src = load_idx_nt(idx, eg, is64);
        int dst = load_idx_nt(idx, num_edges + eg, is64);
        const float4 v = *(const float4*)(x + (long long)src * D + quad * 4);
        float* o = out + (long long)dst * D + quad * 4;
        unsafeAtomicAdd(o + 0, v.x);
        unsafeAtomicAdd(o + 1, v.y);
        unsafeAtomicAdd(o + 2, v.z);
        unsafeAtomicAdd(o + 3, v.w);
    }
}

extern "C" void kernel_launch(void* const* d_in, const int* in_sizes, int n_in,
                              void* d_out, int out_size, void* d_ws, size_t ws_size,
                              hipStream_t stream) {
    const float* x = (const float*)d_in[0];
    const void* up_idx = d_in[1];
    const void* down_idx = d_in[2];
    float* out = (float*)d_out;

    const int E = in_sizes[1] / 2;   // [2, E]
    const int N = out_size / D;      // [N, 64]
    const int NB = (N + NPB - 1) / NPB;
    const long long Etot = 2LL * E;

    // src tile shift: 8192 rows (2MB) preferred; coarsen so NT <= MAXT
    int shift = 13;
    while ((((long long)(N - 1) >> shift) + 1) > MAXT) shift++;
    const int NT = (int)(((long long)(N - 1) >> shift) + 1);

    // ws layout (ints): flag(64) | counts[NB] | offsets[NB+1] pad | cursors[NB] | packed[2E]
    int* ws_i = (int*)d_ws;
    int* flag = ws_i;
    int* counts = ws_i + 64;
    int* offsets = counts + NB;
    int* cursors = offsets + NB + 15;
    unsigned* packed = (unsigned*)(cursors + NB);
    const size_t ws_need = (size_t)(64 + 3LL * NB + 16 + Etot) * 4 + 64;

    detect_idx_dtype<<<1, 64, 0, stream>>>((const int*)up_idx, flag);

    if (ws_size >= ws_need && N <= (1 << 25) && Etot < (1LL << 31)) {
        hipMemsetAsync(counts, 0, (size_t)NB * sizeof(int), stream);
        bucket_hist_kernel<<<2048, 256, NB * sizeof(int), stream>>>(
            up_idx, down_idx, counts, flag, E, NB);
        scan_kernel<<<1, 1024, 0, stream>>>(counts, offsets, cursors, NB);
        const int sblocks = (int)((Etot + CHUNK - 1) / CHUNK);
        bucket_scatter_kernel<<<sblocks, 512, 2 * NB * sizeof(int), stream>>>(
            up_idx, down_idx, cursors, packed, flag, E, NB);
        const int nbins = NT * NPB;
        const size_t glds = (size_t)(CH + 2 * nbins + 4) * 4;
        bucket_gather_kernel<<<NB, 256, glds, stream>>>(
            x, offsets, packed, out, N, shift, NT);
    } else {
        hipMemsetAsync(d_out, 0, (size_t)out_size * sizeof(float), stream);
        scatter_add_kernel<<<8192, 256, 0, stream>>>(x, up_idx, down_idx, out, flag, E);
    }
}